// Round 3
// baseline (273.449 us; speedup 1.0000x reference)
//
#include <hip/hip_runtime.h>

#define B_N   262144
#define PMIN_F 0.001f
#define LOG2E 1.44269504088896340736f
#define LN2   0.69314718055994530942f

typedef _Float16 half4v __attribute__((ext_vector_type(4)));
typedef _Float16 half8  __attribute__((ext_vector_type(8)));
typedef float    floatx4 __attribute__((ext_vector_type(4)));

__device__ __forceinline__ float fexp2(float x) { return __builtin_amdgcn_exp2f(x); }
__device__ __forceinline__ float flog2(float x) { return __builtin_amdgcn_logf(x); }
__device__ __forceinline__ float frcp (float x) { return __builtin_amdgcn_rcpf(x); }

// Scheduling fence: loads batched above this line may not sink below it.
#define SB() __builtin_amdgcn_sched_barrier(0)

// ---------------------------------------------------------------------------
// Prep: weights fp32 -> f16 in MFMA B-fragment order (unchanged).
//   r in [0,8)   : mm1 W1 16x128, K padded to 32; k==16 row carries b1
//   r in [8,40)  : mm2 Wh 128x128
//   r in [40,104): mm3 Wo 128x248 column-remapped to 256 (31->32 pad per d)
// ---------------------------------------------------------------------------
__global__ __launch_bounds__(64) void prep_kernel(
    const float* __restrict__ W1s, const float* __restrict__ b1s,
    const float* __restrict__ Whs, const float* __restrict__ Wos,
    _Float16* __restrict__ ws)
{
    const int bid   = blockIdx.x;          // 0..415
    const int layer = bid / 104;
    const int r     = bid % 104;
    const int lane  = threadIdx.x;
    const int kg    = lane >> 4;
    const int c     = lane & 15;

    half8 v;
    if (r < 8) {
        const int nt = r, n = nt * 16 + c;
        const float* W1 = W1s + layer * 16 * 128;
        const float* b1 = b1s + layer * 128;
        #pragma unroll
        for (int j = 0; j < 8; ++j) {
            const int k = kg * 8 + j;
            v[j] = (k < 16) ? (_Float16)W1[k * 128 + n]
                 : (k == 16) ? (_Float16)b1[n] : (_Float16)0.f;
        }
    } else if (r < 40) {
        const int f = r - 8, nt = f >> 2, ks = f & 3, n = nt * 16 + c;
        const float* Wh = Whs + layer * 128 * 128;
        #pragma unroll
        for (int j = 0; j < 8; ++j) {
            const int k = ks * 32 + kg * 8 + j;
            v[j] = (_Float16)Wh[k * 128 + n];
        }
    } else {
        const int f = r - 40, nt = f >> 2, ks = f & 3, n = nt * 16 + c;
        const int dd = n >> 5, cc = n & 31;
        const float* Wo = Wos + layer * 128 * 248;
        #pragma unroll
        for (int j = 0; j < 8; ++j) {
            const int k = ks * 32 + kg * 8 + j;
            v[j] = (cc < 31) ? (_Float16)Wo[k * 248 + dd * 31 + cc] : (_Float16)0.f;
        }
    }
    *(half8*)(ws + (size_t)bid * 512 + lane * 8) = v;
}

// ---------------------------------------------------------------------------
// Spline for one item (math byte-identical to the verified 225us kernel).
// Rf points at this tile's f32 theta overlay; base = row*68 + dl*32.
// ---------------------------------------------------------------------------
__device__ __forceinline__ void spline_eval(const float* __restrict__ Rf, const int base,
                                            const float x2, float& yout, float& ljout)
{
    const float4 v0 = *(const float4*)&Rf[base];
    const float4 v1 = *(const float4*)&Rf[base + 4];
    const float4 v2 = *(const float4*)&Rf[base + 8];
    const float4 v3 = *(const float4*)&Rf[base + 12];
    const float4 v4 = *(const float4*)&Rf[base + 16];

    float tw[10] = {v0.x, v0.y, v0.z, v0.w, v1.x, v1.y, v1.z, v1.w, v2.x, v2.y};
    float m1 = tw[0];
    #pragma unroll
    for (int i = 1; i < 10; ++i) m1 = fmaxf(m1, tw[i]);
    float se = 0.f;
    #pragma unroll
    for (int i = 0; i < 10; ++i) { tw[i] = fexp2((tw[i] - m1) * LOG2E); se += tw[i]; }
    const float inv198 = 1.98f * frcp(se);   // 2*(1-PMIN*K)/sum

    int cnt = 0;
    {
        float run = -1.f;
        cnt += (run < x2) ? 1 : 0;
        #pragma unroll
        for (int i = 0; i < 10; ++i) {
            run = run + fmaf(tw[i], inv198, 0.002f);
            cnt += (run < x2) ? 1 : 0;
        }
    }
    const int bidx = cnt - 1;
    const bool inb = (bidx >= 0) && (bidx < 10);
    const int ci = bidx < 0 ? 0 : (bidx > 9 ? 9 : bidx);

    float xlo = -1.f, xhi = 0.f, rx;
    {
        float run = -1.f;
        #pragma unroll
        for (int i = 0; i < 10; ++i) {
            const bool pick = (i == ci);
            xlo = pick ? run : xlo;
            run = run + fmaf(tw[i], inv198, 0.002f);
            xhi = pick ? run : xhi;
        }
        rx = run;
    }

    float hh[10] = {v2.z, v2.w, v3.x, v3.y, v3.z, v3.w, v4.x, v4.y, v4.z, v4.w};
    float hm = hh[0];
    #pragma unroll
    for (int i = 1; i < 10; ++i) hm = fmaxf(hm, hh[i]);
    float seh = 0.f;
    #pragma unroll
    for (int i = 0; i < 10; ++i) { hh[i] = fexp2((hh[i] - hm) * LOG2E); seh += hh[i]; }
    const float invh = 1.98f * frcp(seh);
    float ylo = -1.f, yhi = 0.f, ry;
    {
        float run = -1.f;
        #pragma unroll
        for (int i = 0; i < 10; ++i) {
            const bool pick = (i == ci);
            ylo = pick ? run : ylo;
            run = run + fmaf(hh[i], invh, 0.002f);
            yhi = pick ? run : yhi;
        }
        ry = run;
    }

    const float xw = xhi - xlo, yw = yhi - ylo;

    const float u1 = Rf[base + 20 + ci];
    const float u2 = Rf[base + 21 + ci];
    const float t1 = u1 * LOG2E;
    const float t2s = u2 * LOG2E;
    const float dd1 = PMIN_F + 0.999f * ((t1  > 15.f) ? t1  : flog2(1.f + fexp2(t1)));
    const float dd2 = PMIN_F + 0.999f * ((t2s > 15.f) ? t2s : flog2(1.f + fexp2(t2s)));

    const float xs  = inb ? x2 : (xlo + 0.5f * xw);
    const float rxw = frcp(xw);
    const float s   = yw * rxw;
    const float eta = (xs - xlo) * rxw;
    const float rev = 1.f - eta;
    const float er  = eta * rev;
    const float dn  = s + (dd1 + dd2 - 2.f * s) * er;
    const float yrq = ylo + yw * (s * eta * eta + dd1 * er) * frcp(dn);
    const float jn  = s * s * (dd2 * eta * eta + 2.f * s * er + dd1 * rev * rev);
    const float ljx = LN2 * (flog2(jn) - 2.f * flog2(dn));
    const float ylin = (ry + 1.f) * frcp(rx + 1.f) * (x2 + 1.f) - 1.f;

    yout  = inb ? yrq : ylin;
    ljout = inb ? ljx : 0.f;
}

// ---------------------------------------------------------------------------
// Main: verified 2-tile structure. Round-3 change: weight-load batches are
// PINNED with sched_barrier(0) (round 2 showed the scheduler sank them:
// VGPR stayed 84) and placed for overlap:
//   - mm1: bf1[8] up front.
//   - mm2: g0 batch after mm1 stores; g1 batch issues under g0's MFMAs.
//   - mm3: qd0 batch issues before a3 pulls + barrier; qd+1 batch issues
//     right after qd's MFMAs, so the spline VALU section covers its latency.
// Register audit: peak ~150-165 live < 170 cap pinned by launch_bounds(64,3).
// Math/layout/barriers byte-identical to the verified kernel. LDS 10752 B.
// ---------------------------------------------------------------------------
__global__ __launch_bounds__(64, 3) void flow_mfma(
    const float* __restrict__ x_in,
    const float* __restrict__ c_in,
    const float* __restrict__ bhs,
    const float* __restrict__ bos,
    const int*   __restrict__ perms,
    const _Float16* __restrict__ wsW,
    float* __restrict__ out)
{
    __shared__ __align__(16) float    xls[2][256];   // [tile][16 rows][16]
    __shared__ __align__(16) _Float16 R[2][2176];    // h(f16,132) / theta(f32,68)

    const int lane = threadIdx.x;
    const int q    = lane >> 4;
    const int m    = lane & 15;
    const long long row0 = (long long)blockIdx.x * 32;

    {
        const float4* xp = (const float4*)(x_in + row0 * 16);
        *(float4*)&xls[0][lane * 4] = xp[lane];
        *(float4*)&xls[1][lane * 4] = xp[lane + 64];
    }

    // layer-invariant part of the mm1 A-fragment (c data / bias-one)
    half8 a1c[2];
    #pragma unroll
    for (int t2 = 0; t2 < 2; ++t2) {
        #pragma unroll
        for (int j = 0; j < 8; ++j) a1c[t2][j] = (_Float16)0.f;
        if (q == 1) {
            const float4* cp = (const float4*)(c_in + (row0 + t2 * 16 + m) * 8);
            const float4 c0 = cp[0], c1 = cp[1];
            a1c[t2][0] = (_Float16)c0.x; a1c[t2][1] = (_Float16)c0.y;
            a1c[t2][2] = (_Float16)c0.z; a1c[t2][3] = (_Float16)c0.w;
            a1c[t2][4] = (_Float16)c1.x; a1c[t2][5] = (_Float16)c1.y;
            a1c[t2][6] = (_Float16)c1.z; a1c[t2][7] = (_Float16)c1.w;
        } else if (q == 2) {
            a1c[t2][0] = (_Float16)1.f;   // k=16 -> bias row
        }
    }

    // spline item mapping (fixed per lane): tile, row, d-parity
    const int sp_t2  = lane >> 5;
    const int sp_row = (lane & 31) >> 1;
    const int sp_dl  = lane & 1;

    float ljacc = 0.f;

    for (int l = 0; l < 4; ++l) {
        const _Float16* wsl = wsW + (size_t)l * 104 * 512;
        const float* bh = bhs + l * 128;
        const float* bo = bos + l * 248;

        // ---- batched prefetch: all 8 mm1 b-fragments, pinned --------------
        half8 bf1[8];
        #pragma unroll
        for (int i = 0; i < 8; ++i)
            bf1[i] = *(const half8*)(wsl + i * 512 + lane * 8);
        SB();

        // ================= mm1: [x1,c,1] @ [W1;b1] -> h1 (f16) =============
        half8 a1[2];
        #pragma unroll
        for (int t2 = 0; t2 < 2; ++t2) {
            a1[t2] = a1c[t2];
            if (q == 0) {
                const float4 lo = *(const float4*)&xls[t2][m * 16];
                const float4 hi = *(const float4*)&xls[t2][m * 16 + 4];
                a1[t2][0] = (_Float16)lo.x; a1[t2][1] = (_Float16)lo.y;
                a1[t2][2] = (_Float16)lo.z; a1[t2][3] = (_Float16)lo.w;
                a1[t2][4] = (_Float16)hi.x; a1[t2][5] = (_Float16)hi.y;
                a1[t2][6] = (_Float16)hi.z; a1[t2][7] = (_Float16)hi.w;
            }
        }
        #pragma unroll
        for (int g = 0; g < 2; ++g) {
            const floatx4 z = {0.f, 0.f, 0.f, 0.f};
            floatx4 acc0[4], acc1[4];
            #pragma unroll
            for (int nt = 0; nt < 4; ++nt) {
                acc0[nt] = __builtin_amdgcn_mfma_f32_16x16x32_f16(a1[0], bf1[g * 4 + nt], z, 0, 0, 0);
                acc1[nt] = __builtin_amdgcn_mfma_f32_16x16x32_f16(a1[1], bf1[g * 4 + nt], z, 0, 0, 0);
            }
            #pragma unroll
            for (int nt = 0; nt < 4; ++nt)
                #pragma unroll
                for (int reg = 0; reg < 4; ++reg) {
                    R[0][(q * 4 + reg) * 132 + (g * 4 + nt) * 16 + m] = (_Float16)fmaxf(acc0[nt][reg], 0.f);
                    R[1][(q * 4 + reg) * 132 + (g * 4 + nt) * 16 + m] = (_Float16)fmaxf(acc1[nt][reg], 0.f);
                }
        }

        // ---- batched prefetch: mm2 g0's 16 b-fragments, pinned ------------
        half8 bf2a[16];
        #pragma unroll
        for (int i = 0; i < 16; ++i)
            bf2a[i] = *(const half8*)(wsl + (8 + i) * 512 + lane * 8);
        SB();

        // ===== mm2: pull h1 A-frags (in-order LDS, no barrier needed) ======
        half8 a2[2][4];
        #pragma unroll
        for (int t2 = 0; t2 < 2; ++t2)
            #pragma unroll
            for (int ks = 0; ks < 4; ++ks) {
                const half4v lo = *(const half4v*)&R[t2][m * 132 + ks * 32 + q * 8];
                const half4v hi = *(const half4v*)&R[t2][m * 132 + ks * 32 + q * 8 + 4];
                a2[t2][ks] = __builtin_shufflevector(lo, hi, 0, 1, 2, 3, 4, 5, 6, 7);
            }

        // ----- mm2 g0: MFMAs on bf2a; g1 batch issues underneath -----------
        floatx4 accA0[4], accA1[4];
        #pragma unroll
        for (int nt = 0; nt < 4; ++nt) {
            const float bb = bh[nt * 16 + m];
            accA0[nt][0] = bb; accA0[nt][1] = bb; accA0[nt][2] = bb; accA0[nt][3] = bb;
            accA1[nt] = accA0[nt];
        }
        #pragma unroll
        for (int ks = 0; ks < 4; ++ks)
            #pragma unroll
            for (int nt = 0; nt < 4; ++nt) {
                accA0[nt] = __builtin_amdgcn_mfma_f32_16x16x32_f16(a2[0][ks], bf2a[nt * 4 + ks], accA0[nt], 0, 0, 0);
                accA1[nt] = __builtin_amdgcn_mfma_f32_16x16x32_f16(a2[1][ks], bf2a[nt * 4 + ks], accA1[nt], 0, 0, 0);
            }

        // ---- batched prefetch: mm2 g1's 16 b-fragments, pinned ------------
        half8 bf2b[16];
        #pragma unroll
        for (int i = 0; i < 16; ++i)
            bf2b[i] = *(const half8*)(wsl + (24 + i) * 512 + lane * 8);
        SB();

        #pragma unroll
        for (int nt = 0; nt < 4; ++nt)
            #pragma unroll
            for (int reg = 0; reg < 4; ++reg) {
                R[0][(q * 4 + reg) * 132 + nt * 16 + m] = (_Float16)fmaxf(accA0[nt][reg], 0.f);
                R[1][(q * 4 + reg) * 132 + nt * 16 + m] = (_Float16)fmaxf(accA1[nt][reg], 0.f);
            }

        // ----- mm2 g1 ------------------------------------------------------
        floatx4 accB0[4], accB1[4];
        #pragma unroll
        for (int nt = 0; nt < 4; ++nt) {
            const float bb = bh[(4 + nt) * 16 + m];
            accB0[nt][0] = bb; accB0[nt][1] = bb; accB0[nt][2] = bb; accB0[nt][3] = bb;
            accB1[nt] = accB0[nt];
        }
        #pragma unroll
        for (int ks = 0; ks < 4; ++ks)
            #pragma unroll
            for (int nt = 0; nt < 4; ++nt) {
                accB0[nt] = __builtin_amdgcn_mfma_f32_16x16x32_f16(a2[0][ks], bf2b[nt * 4 + ks], accB0[nt], 0, 0, 0);
                accB1[nt] = __builtin_amdgcn_mfma_f32_16x16x32_f16(a2[1][ks], bf2b[nt * 4 + ks], accB1[nt], 0, 0, 0);
            }
        #pragma unroll
        for (int nt = 0; nt < 4; ++nt)
            #pragma unroll
            for (int reg = 0; reg < 4; ++reg) {
                R[0][(q * 4 + reg) * 132 + (4 + nt) * 16 + m] = (_Float16)fmaxf(accB0[nt][reg], 0.f);
                R[1][(q * 4 + reg) * 132 + (4 + nt) * 16 + m] = (_Float16)fmaxf(accB1[nt][reg], 0.f);
            }

        // ---- batched prefetch: mm3 quarter-0's 16 b-fragments, pinned.
        //      Overlaps the a3 pulls + barrier below.
        half8 bf3[16];
        #pragma unroll
        for (int i = 0; i < 16; ++i)
            bf3[i] = *(const half8*)(wsl + (40 + i) * 512 + lane * 8);
        SB();

        // ===== mm3: pull h2 A-frags to regs ===============================
        half8 a3[2][4];
        #pragma unroll
        for (int t2 = 0; t2 < 2; ++t2)
            #pragma unroll
            for (int ks = 0; ks < 4; ++ks) {
                const half4v lo = *(const half4v*)&R[t2][m * 132 + ks * 32 + q * 8];
                const half4v hi = *(const half4v*)&R[t2][m * 132 + ks * 32 + q * 8 + 4];
                a3[t2][ks] = __builtin_shufflevector(lo, hi, 0, 1, 2, 3, 4, 5, 6, 7);
            }
        __syncthreads();   // FENCE: f16 h-reads above vs f32 theta-writes below

        float* Rf0 = (float*)&R[0][0];
        float* Rf1 = (float*)&R[1][0];

        #pragma unroll
        for (int qd = 0; qd < 4; ++qd) {
            // ---- mm3 quarter: cols [qd*64, qd*64+64) = d in {qd*2, qd*2+1}
            floatx4 acc0[4], acc1[4];
            {
                #pragma unroll
                for (int j = 0; j < 4; ++j) {
                    const int n = qd * 64 + j * 16 + m;
                    const int cc = n & 31;
                    const float bb = (cc < 31) ? bo[(n >> 5) * 31 + cc] : 0.f;
                    acc0[j][0] = bb; acc0[j][1] = bb; acc0[j][2] = bb; acc0[j][3] = bb;
                    acc1[j] = acc0[j];
                }
                #pragma unroll
                for (int ks = 0; ks < 4; ++ks)
                    #pragma unroll
                    for (int j = 0; j < 4; ++j) {
                        acc0[j] = __builtin_amdgcn_mfma_f32_16x16x32_f16(a3[0][ks], bf3[j * 4 + ks], acc0[j], 0, 0, 0);
                        acc1[j] = __builtin_amdgcn_mfma_f32_16x16x32_f16(a3[1][ks], bf3[j * 4 + ks], acc1[j], 0, 0, 0);
                    }
            }

            // ---- prefetch next quarter's b-fragments, pinned; the theta
            //      stores + spline below cover their L2 latency -------------
            if (qd < 3) {
                #pragma unroll
                for (int i = 0; i < 16; ++i)
                    bf3[i] = *(const half8*)(wsl + (40 + (qd + 1) * 16 + i) * 512 + lane * 8);
                SB();
            }

            // ---- theta stores (f32): addr = row*68 + (j>>1)*32 + ((j&1)*16+m)
            #pragma unroll
            for (int j = 0; j < 4; ++j) {
                const int off = (j >> 1) * 32 + (j & 1) * 16 + m;
                #pragma unroll
                for (int reg = 0; reg < 4; ++reg) {
                    Rf0[(q * 4 + reg) * 68 + off] = acc0[j][reg];
                    Rf1[(q * 4 + reg) * 68 + off] = acc1[j][reg];
                }
            }

            // ---- spline quarter: 64 items, 1/lane: (sp_t2, sp_row, d) -----
            {
                const int d    = qd * 2 + sp_dl;
                const int base = sp_row * 68 + sp_dl * 32;
                const float* Rf = sp_t2 ? Rf1 : Rf0;
                const int xi   = sp_row * 16 + 8 + d;

                float yv, lj;
                spline_eval(Rf, base, xls[sp_t2][xi], yv, lj);
                xls[sp_t2][xi] = yv;
                ljacc += lj;
            }
        }

        // ================= permutation (in-order LDS, same-type) ===========
        {
            const int4 pv = ((const int4*)(perms + l * 16))[lane & 3];
            const int mm = lane >> 2;
            const float a0 = xls[0][mm * 16 + pv.x];
            const float a1v = xls[0][mm * 16 + pv.y];
            const float a2v = xls[0][mm * 16 + pv.z];
            const float a3v = xls[0][mm * 16 + pv.w];
            const float b0 = xls[1][mm * 16 + pv.x];
            const float b1v = xls[1][mm * 16 + pv.y];
            const float b2 = xls[1][mm * 16 + pv.z];
            const float b3 = xls[1][mm * 16 + pv.w];
            *(float4*)&xls[0][lane * 4] = make_float4(a0, a1v, a2v, a3v);
            *(float4*)&xls[1][lane * 4] = make_float4(b0, b1v, b2, b3);
        }
        __syncthreads();   // FENCE: f32 theta-reads this layer vs f16 h-writes next
    }

    // ---- outputs: x [B,16] then ljd [B]
    #pragma unroll
    for (int t2 = 0; t2 < 2; ++t2) {
        const float4 vo = *(const float4*)&xls[t2][lane * 4];
        ((float4*)(out + (row0 + t2 * 16) * 16))[lane] = vo;
    }
    {
        const float ljs = ljacc + __shfl_xor(ljacc, 1);
        if ((lane & 1) == 0)
            out[(size_t)B_N * 16 + row0 + sp_t2 * 16 + sp_row] = ljs;
    }
}

extern "C" void kernel_launch(void* const* d_in, const int* in_sizes, int n_in,
                              void* d_out, int out_size, void* d_ws, size_t ws_size,
                              hipStream_t stream) {
    const float* x     = (const float*)d_in[0];
    const float* c     = (const float*)d_in[1];
    const float* W1s   = (const float*)d_in[2];
    const float* b1s   = (const float*)d_in[3];
    const float* Whs   = (const float*)d_in[4];
    const float* bhs   = (const float*)d_in[5];
    const float* Wos   = (const float*)d_in[6];
    const float* bos   = (const float*)d_in[7];
    const int*   perms = (const int*)d_in[8];
    float* out = (float*)d_out;
    _Float16* ws = (_Float16*)d_ws;

    prep_kernel<<<dim3(416), dim3(64), 0, stream>>>(W1s, b1s, Whs, Wos, ws);
    flow_mfma<<<dim3(B_N / 32), dim3(64), 0, stream>>>(
        x, c, bhs, bos, perms, ws, out);
}